// Round 4
// baseline (287.091 us; speedup 1.0000x reference)
//
#include <hip/hip_runtime.h>

// R19: BISECT round. R16-R18 (pipelined 9-dot reconstruction) all failed with
// large, build-varying absmax; R17 even showed run-to-run variation (468 vs
// 389) => race/transport signature, NOT numerics (fp64 R18 failed identically;
// cancellation ratio measured ~1.15x/step, cannot amplify 1e-7 to 644).
// Four audits of the algebra & sync graph found nothing => stop auditing,
// bisect. This kernel = R15's EXACT algorithm (depth-0: post TRUE post-update
// gamma/delta at end of iter k, consume at iter k+1 after the SpMV) carried
// on the NEW transport (tagged 48-bit-fp64 ring, RING=4, 4-wave consume,
// thread-0 tagged post + flag).
//   PASS => transport proven; bug is isolated to the early-post/
//           reconstruction dataflow. FAIL => transport indicted (~40 lines).
// Prediction on PASS: absmax ~0.1 (fp64 dots), dispatch ~180-188 us.

#define HH 1024
#define WW 1024
#define CG_STEPS 50
#define NB 256        // one block per CU; each block owns 4 grid rows
#define NT 1024       // one thread per column (16 waves)
#define RING 4        // reduction ring depth (ample: reader/overwriter skew <=1)

#define SCOPE __HIP_MEMORY_SCOPE_AGENT

__device__ __forceinline__ float aload(const float* p) {
    return __hip_atomic_load(p, __ATOMIC_RELAXED, SCOPE);
}
__device__ __forceinline__ void astore(float* p, float v) {
    __hip_atomic_store(p, v, __ATOMIC_RELAXED, SCOPE);
}
__device__ __forceinline__ int iload(const int* p) {
    return __hip_atomic_load(p, __ATOMIC_RELAXED, SCOPE);
}
__device__ __forceinline__ void istore(int* p, int v) {
    __hip_atomic_store(p, v, __ATOMIC_RELAXED, SCOPE);
}
__device__ __forceinline__ unsigned long long uload(const unsigned long long* p) {
    return __hip_atomic_load(p, __ATOMIC_RELAXED, SCOPE);
}
__device__ __forceinline__ void ustore(unsigned long long* p, unsigned long long v) {
    __hip_atomic_store(p, v, __ATOMIC_RELAXED, SCOPE);
}

// tagged 48-bit double: [tag:16][bits(d)>>16:48]. tag <= 50; 0xAA-poison top16
// = 0xAAAA != any tag; stale tags != wanted tag. Truncation rel err 2^-36.
__device__ __forceinline__ unsigned long long packtd(unsigned tag, double d) {
    return ((unsigned long long)tag << 48) |
           (((unsigned long long)__double_as_longlong(d)) >> 16);
}
__device__ __forceinline__ double unpacktd(unsigned long long v) {
    return __longlong_as_double((long long)(v << 16));
}

__global__ __launch_bounds__(NT)
void cgsolve_kernel(const int* __restrict__ cols, const float* __restrict__ vals,
                    const float* __restrict__ b, float* __restrict__ xout,
                    float* __restrict__ rbuf,
                    unsigned long long* __restrict__ redr,
                    int* __restrict__ flags) {
    const int col = threadIdx.x;
    const int bb  = blockIdx.x;

    __shared__ float  sr[4][WW + 1];
    __shared__ double sa[16][2];       // post-side wave partials (fp64)
    __shared__ double sc[4][2];        // consume-side per-wave partials (fp64)
    __shared__ int    scols[2][5 * WW];
    __shared__ float  svals[2][5 * WW];

    float adiag[4], art[4], alf[4], adn[4], awu[4];
    float x_[4], r_[4], w_[4], q_[4];
    float p_[4] = {0.f, 0.f, 0.f, 0.f};
    float s_[4] = {0.f, 0.f, 0.f, 0.f};
    float z_[4] = {0.f, 0.f, 0.f, 0.f};

    // ---- prologue: LDS-staged MATCHED COO parse (decode by col value — no
    // entry-order assumption; R7's positional variant failed on HW). Two rows
    // staged per round with int2/float2 vector loads (alignment proven R15).
    for (int half = 0; half < 2; ++half) {
        __syncthreads();                       // protect LDS reuse across rounds
        #pragma unroll
        for (int rr2 = 0; rr2 < 2; ++rr2) {
            const int i    = 4 * bb + 2 * half + rr2;
            const int off  = (i == 0) ? 0 : (4 * WW - 2) + (i - 1) * (5 * WW - 2);
            const int base = 1 + (i > 0) + (i < HH - 1);
            const int len2 = (base * WW + 2 * WW - 2) >> 1;   // int2 count
            const int2*   gc = (const int2*)(cols + off);
            const float2* gv = (const float2*)(vals + off);
            int2*   lc = (int2*)scols[rr2];
            float2* lv = (float2*)svals[rr2];
            for (int e = threadIdx.x; e < len2; e += NT) {
                lc[e] = gc[e];
                lv[e] = gv[e];
            }
        }
        __syncthreads();
        #pragma unroll
        for (int rr2 = 0; rr2 < 2; ++rr2) {
            const int rr     = 2 * half + rr2;
            const int i      = 4 * bb + rr;
            const int base   = 1 + (i > 0) + (i < HH - 1);
            const int j      = col;
            const int within = (j == 0) ? 0 : (base + 1) + (j - 1) * (base + 2);
            const int nnz    = base + (j > 0) + (j < WW - 1);
            const int t      = i * WW + j;
            float dg = 0.f, wr = 0.f, wl = 0.f, wd = 0.f, wu = 0.f;
            #pragma unroll
            for (int e = 0; e < 5; ++e) {
                if (e < nnz) {
                    const int   c = scols[rr2][within + e];
                    const float v = svals[rr2][within + e];
                    if (c == t)           dg = v;
                    else if (c == t + 1)  wr = v;
                    else if (c == t - 1)  wl = v;
                    else if (c == t + WW) wd = v;
                    else if (c == t - WW) wu = v;
                }
            }
            adiag[rr] = dg; art[rr] = wr; alf[rr] = wl; adn[rr] = wd; awu[rr] = wu;
            r_[rr] = b[t];
            x_[rr] = 0.f;
        }
    }

    // ---- setup: w0 = A r0 (halos straight from b); publish halo0; post
    // tag 0 = (gamma0, delta0) in fp64 + flag 1. Structure identical to the
    // R15-proven blockPartialPost: halo stores, ONE barrier (drains vmem),
    // lanes 0..15 finish, thread 0 stores reduction + flag.
    {
        #pragma unroll
        for (int rr = 0; rr < 4; ++rr) sr[rr][col] = r_[rr];
        __syncthreads();
        const float btop = (bb > 0)      ? b[(4 * bb - 1) * WW + col] : 0.f;
        const float bbot = (bb < NB - 1) ? b[(4 * bb + 4) * WW + col] : 0.f;
        double rs_d = 0.0, dl_d = 0.0;
        #pragma unroll
        for (int rr = 0; rr < 4; ++rr) {
            float sum = adiag[rr] * r_[rr];
            const float vr = (col < WW - 1) ? sr[rr][col + 1] : 0.f;
            const float vl = (col > 0)      ? sr[rr][col - 1] : 0.f;
            sum += art[rr] * vr + alf[rr] * vl;
            const float vd = (rr < 3) ? r_[rr + 1] : bbot;
            const float vu = (rr > 0) ? r_[rr - 1] : btop;
            sum += adn[rr] * vd + awu[rr] * vu;
            w_[rr] = sum;
            rs_d += (double)r_[rr] * r_[rr];
            dl_d += (double)sum * r_[rr];
        }
        astore(&rbuf[(2 * bb + 0) * WW + col], w_[0]);   // halo 0, buffer 0
        astore(&rbuf[(2 * bb + 1) * WW + col], w_[3]);
        #pragma unroll
        for (int mask = 1; mask < 64; mask <<= 1) {
            rs_d += __shfl_xor(rs_d, mask, 64);
            dl_d += __shfl_xor(dl_d, mask, 64);
        }
        const int lane = threadIdx.x & 63, wid = threadIdx.x >> 6;
        if (lane == 0) { sa[wid][0] = rs_d; sa[wid][1] = dl_d; }
        __syncthreads();                       // drains halo stores < flag
        if (threadIdx.x < 16) {
            double t0 = sa[threadIdx.x][0], t1 = sa[threadIdx.x][1];
            #pragma unroll
            for (int mask = 1; mask < 16; mask <<= 1) {
                t0 += __shfl_xor(t0, mask, 16);
                t1 += __shfl_xor(t1, mask, 16);
            }
            if (threadIdx.x == 0) {
                unsigned long long* bp = redr + bb;      // slot 0
                ustore(bp,      packtd(0u, t0));
                ustore(bp + NB, packtd(0u, t1));
                istore(&flags[bb], 1);
            }
        }
    }

    double gamma_prev = 1.0, alpha_prev = 1.0;

    #pragma unroll 1
    for (int k = 0; k < CG_STEPS; ++k) {
        if (k < CG_STEPS - 1) {
            // ---- stage w_k into LDS, poll neighbor halo flags, ONE barrier,
            // then read LDS + halos and compute q = A w (R15-proven shape).
            #pragma unroll
            for (int rr = 0; rr < 4; ++rr) sr[rr][col] = w_[rr];
            if (threadIdx.x < 2) {
                const int nb2 = bb + (threadIdx.x ? 1 : -1);
                if (nb2 >= 0 && nb2 < NB)
                    while (iload(&flags[nb2]) < k + 1) __builtin_amdgcn_s_sleep(1);
            }
            __syncthreads();                   // barrier1
            const float* hb = rbuf + (size_t)(k & 1) * 2 * NB * WW;
            const float wtop = (bb > 0)
                ? aload(&hb[(2 * (bb - 1) + 1) * WW + col]) : 0.f;
            const float wbot = (bb < NB - 1)
                ? aload(&hb[(2 * (bb + 1) + 0) * WW + col]) : 0.f;
            #pragma unroll
            for (int rr = 0; rr < 4; ++rr) {
                float sum = adiag[rr] * w_[rr];
                const float vr = (col < WW - 1) ? sr[rr][col + 1] : 0.f;
                const float vl = (col > 0)      ? sr[rr][col - 1] : 0.f;
                sum += art[rr] * vr + alf[rr] * vl;
                const float vd = (rr < 3) ? w_[rr + 1] : wbot;
                const float vu = (rr > 0) ? w_[rr - 1] : wtop;
                sum += adn[rr] * vd + awu[rr] * vu;
                q_[rr] = sum;
            }
        }

        // ---- consume tag k from ring slot k&3 (posted end of iter k-1, or
        // setup for k=0): 4-wave consume, one source block per thread,
        // self-validating tags (stale/poison both fail the tag check).
        double gam, del;
        {
            if (threadIdx.x < NB) {
                const unsigned want = (unsigned)k;
                const unsigned long long* bp =
                    redr + (size_t)(k & (RING - 1)) * 2 * NB + threadIdx.x;
                unsigned long long v0 = uload(bp);
                unsigned long long v1 = uload(bp + NB);
                while ((unsigned)(v0 >> 48) != want ||
                       (unsigned)(v1 >> 48) != want) {
                    __builtin_amdgcn_s_sleep(1);
                    if ((unsigned)(v0 >> 48) != want) v0 = uload(bp);
                    if ((unsigned)(v1 >> 48) != want) v1 = uload(bp + NB);
                }
                double t0 = unpacktd(v0), t1 = unpacktd(v1);
                #pragma unroll
                for (int mask = 1; mask < 64; mask <<= 1) {
                    t0 += __shfl_xor(t0, mask, 64);
                    t1 += __shfl_xor(t1, mask, 64);
                }
                if ((threadIdx.x & 63) == 0) {
                    const int g = threadIdx.x >> 6;
                    sc[g][0] = t0; sc[g][1] = t1;
                }
            }
            __syncthreads();               // barrierC
            gam = ((sc[0][0] + sc[1][0]) + sc[2][0]) + sc[3][0];
            del = ((sc[0][1] + sc[1][1]) + sc[2][1]) + sc[3][1];
        }

        const double beta  = (k == 0) ? 0.0 : gam / gamma_prev;
        const double alpha = (k == 0) ? gam / del
                                      : gam / (del - beta * gam / alpha_prev);
        const float betaf = (float)beta, alphaf = (float)alpha;
        #pragma unroll
        for (int rr = 0; rr < 4; ++rr) {
            p_[rr] = r_[rr] + betaf * p_[rr];
            x_[rr] += alphaf * p_[rr];
        }
        if (k == CG_STEPS - 1) break;

        // ---- updates + TRUE post-update dots (R15 semantics, fp64)
        double rs_d = 0.0, dl_d = 0.0;
        #pragma unroll
        for (int rr = 0; rr < 4; ++rr) {
            z_[rr] = q_[rr] + betaf * z_[rr];
            s_[rr] = w_[rr] + betaf * s_[rr];
            r_[rr] -= alphaf * s_[rr];
            w_[rr] -= alphaf * z_[rr];
            rs_d += (double)r_[rr] * r_[rr];
            dl_d += (double)w_[rr] * r_[rr];
        }
        // publish w-halo k+1 (double-buffered; race-free: we consumed tag k,
        // so every block finished its iter-(k-1) reads of this parity — the
        // R15-proven argument).
        float* hbn = rbuf + (size_t)((k + 1) & 1) * 2 * NB * WW;
        astore(&hbn[(2 * bb + 0) * WW + col], w_[0]);
        astore(&hbn[(2 * bb + 1) * WW + col], w_[3]);
        #pragma unroll
        for (int mask = 1; mask < 64; mask <<= 1) {
            rs_d += __shfl_xor(rs_d, mask, 64);
            dl_d += __shfl_xor(dl_d, mask, 64);
        }
        const int lane = threadIdx.x & 63, wid = threadIdx.x >> 6;
        if (lane == 0) { sa[wid][0] = rs_d; sa[wid][1] = dl_d; }
        __syncthreads();                   // barrier2: drains halo stores < flag
        if (threadIdx.x < 16) {
            double t0 = sa[threadIdx.x][0], t1 = sa[threadIdx.x][1];
            #pragma unroll
            for (int mask = 1; mask < 16; mask <<= 1) {
                t0 += __shfl_xor(t0, mask, 16);
                t1 += __shfl_xor(t1, mask, 16);
            }
            if (threadIdx.x == 0) {
                unsigned long long* bp =
                    redr + (size_t)((k + 1) & (RING - 1)) * 2 * NB + bb;
                ustore(bp,      packtd((unsigned)(k + 1), t0));
                ustore(bp + NB, packtd((unsigned)(k + 1), t1));
                istore(&flags[bb], k + 2);
            }
        }

        gamma_prev = gam; alpha_prev = alpha;
    }

    #pragma unroll
    for (int rr = 0; rr < 4; ++rr)
        xout[(4 * bb + rr) * WW + col] = x_[rr];
}

extern "C" void kernel_launch(void* const* d_in, const int* in_sizes, int n_in,
                              void* d_out, int out_size, void* d_ws, size_t ws_size,
                              hipStream_t stream) {
    const int*   cols = (const int*)d_in[1];
    const float* vals = (const float*)d_in[2];
    const float* b    = (const float*)d_in[3];
    float* x = (float*)d_out;

    // workspace layout — ~4.21 MiB, well under the R15-proven envelope:
    //   rbuf : 2 bufs * 2*NB rows * WW f32           = 4 MiB
    //   redr : RING * 2 * NB u64 (tagged fp64 ring)  = 16 KiB
    //   flags: NB int                                = 1 KiB
    float* rbuf = (float*)d_ws;
    unsigned long long* redr =
        (unsigned long long*)(rbuf + 2 * 2 * (size_t)NB * WW);
    int* flags = (int*)(redr + (size_t)RING * 2 * NB);

    // no memset: 0xAA poison fails the tag check (top16 = 0xAAAA != any
    // tag <= 50) and flags poison is negative (< any k+1).
    //
    // Regular launch: 256 blocks on 256 CUs, 16 waves/CU, ~98 KB LDS (<160)
    // -> 1 block/CU, all blocks resident by capacity (PROVEN R9/R10/R14).
    // Known-bad: R11 NT=1088 (illegal), R12 512-block (deadlock), R13
    // pre-issued polls (nondeterminism), R7 positional parse (wrong on HW),
    // R16-R18 early-post 9-dot reconstruction (failing for a still-unlocated
    // reason — this round bisects transport vs early-post dataflow).
    cgsolve_kernel<<<dim3(NB), dim3(NT), 0, stream>>>(cols, vals, b, x,
                                                      rbuf, redr, flags);
}